// Round 1
// baseline (161.741 us; speedup 1.0000x reference)
//
#include <hip/hip_runtime.h>
#include <math.h>

// Problem constants (match reference setup_inputs)
#define B_N   8192      // samples
#define Z_D   128       // feature dim
#define P_N   93        // proxies
#define NCLS  62        // classes
#define A_N   2730      // anchors: arange(0, 8189, 3)
#define EPSF      1e-6f
#define TWO_EPS   2e-6f
#define ZEPS2     (128.0f * 1e-6f * 1e-6f)

__device__ __forceinline__ float wave_sum(float v) {
#pragma unroll
  for (int off = 1; off < 64; off <<= 1) v += __shfl_xor(v, off, 64);
  return v;
}
__device__ __forceinline__ float wave_min(float v) {
#pragma unroll
  for (int off = 1; off < 64; off <<= 1) v = fminf(v, __shfl_xor(v, off, 64));
  return v;
}

// --- kP: normalize proxies, per-proxy norms/sums, zero accumulator ----------
__global__ void kP(const float* __restrict__ prox, float* __restrict__ prxn,
                   float* __restrict__ pp, float* __restrict__ sp,
                   float* __restrict__ acc) {
  const int row = blockIdx.x;            // 0..92
  const int lane = threadIdx.x;          // 0..63
  float a = prox[row * Z_D + lane];
  float b = prox[row * Z_D + 64 + lane];
  float s = wave_sum(a + b);
  float q = wave_sum(a * a + b * b);
  float norm = sqrtf(q);
  float denom = fmaxf(norm, 1e-12f);
  float inv = 1.0f / denom;
  prxn[row * Z_D + lane] = a * inv;
  prxn[row * Z_D + 64 + lane] = b * inv;
  if (lane == 0) {
    pp[row] = q * inv * inv;   // ||p̂||^2
    sp[row] = s * inv;         // sum(p̂)
    if (row == 0) acc[0] = 0.0f;
  }
}

// --- kZ: per-sample sumsq / sum / relative class ---------------------------
__global__ void kZ(const float* __restrict__ z, const int* __restrict__ y_idx,
                   const int* __restrict__ y_map,
                   float* __restrict__ zz, float* __restrict__ sz,
                   int* __restrict__ yrel) {
  const int wid = (int)((blockIdx.x * blockDim.x + threadIdx.x) >> 6);
  const int lane = threadIdx.x & 63;
  if (wid >= B_N) return;
  float a = z[wid * Z_D + lane];
  float b = z[wid * Z_D + 64 + lane];
  float s = wave_sum(a + b);
  float q = wave_sum(a * a + b * b);
  if (lane == 0) {
    zz[wid] = q;
    sz[wid] = s;
    int yi = y_idx[wid];
    int r = 0;  // argmax over all-false booleans = 0
    for (int m = 0; m < NCLS; ++m) {
      if (y_map[m] == yi) { r = m; break; }
    }
    yrel[wid] = r;
  }
}

// --- kG: G[k][j] = p̂_k · z_j in both layouts ------------------------------
// grid (32 j-blocks, 12 k-tiles), block 256. GT row stride = 96.
__global__ void kG(const float* __restrict__ z, const float* __restrict__ prxn,
                   float* __restrict__ G, float* __restrict__ GT) {
  const int j = blockIdx.x * 256 + threadIdx.x;   // 0..8191
  const int k0 = blockIdx.y * 8;                  // 0,8,...,88
  float acc[8];
#pragma unroll
  for (int kk = 0; kk < 8; ++kk) acc[kk] = 0.0f;
  const float* __restrict__ zrow = z + (size_t)j * Z_D;
  for (int i4 = 0; i4 < Z_D; i4 += 4) {
    const float4 zv = *(const float4*)(zrow + i4);
#pragma unroll
    for (int kk = 0; kk < 8; ++kk) {
      const int k = k0 + kk;
      if (k >= P_N) continue;                     // uniform branch
      const float4 pv = *(const float4*)(prxn + (size_t)k * Z_D + i4);
      acc[kk] += zv.x * pv.x + zv.y * pv.y + zv.z * pv.z + zv.w * pv.w;
    }
  }
#pragma unroll
  for (int kk = 0; kk < 8; ++kk) {
    const int k = k0 + kk;
    if (k < P_N) {
      G[(size_t)k * B_N + j] = acc[kk];           // coalesced over j
      GT[(size_t)j * 96 + k] = acc[kk];           // scattered, small
    }
  }
}

// --- kC: one wave per anchor ----------------------------------------------
__global__ void kC(const float* __restrict__ zz, const float* __restrict__ sz,
                   const int* __restrict__ yrel,
                   const float* __restrict__ pp, const float* __restrict__ sp,
                   const float* __restrict__ G, const float* __restrict__ GT,
                   float* __restrict__ acc) {
  const int wid = (int)((blockIdx.x * blockDim.x + threadIdx.x) >> 6);
  const int lane = threadIdx.x & 63;
  if (wid >= A_N) return;
  const int i = 3 * wid;                 // anchor sample index
  const float zzi = zz[i], szi = sz[i];
  const int cls = yrel[i];
  const int k2 = lane + 64;

  // --- step a: nearest proxy to anchor (argmin, first-index tie-break) ---
  const float* __restrict__ GTi = GT + (size_t)i * 96;
  float v1 = fmaxf(zzi + pp[lane] - 2.0f * GTi[lane] +
                   TWO_EPS * (szi - sp[lane]) + ZEPS2, 0.0f);
  int i1 = lane;
  if (k2 < P_N) {
    float v2 = fmaxf(zzi + pp[k2] - 2.0f * GTi[k2] +
                     TWO_EPS * (szi - sp[k2]) + ZEPS2, 0.0f);
    if (v2 < v1) { v1 = v2; i1 = k2; }
  }
#pragma unroll
  for (int off = 1; off < 64; off <<= 1) {
    float ov = __shfl_xor(v1, off, 64);
    int oi = __shfl_xor(i1, off, 64);
    if (ov < v1 || (ov == v1 && oi < i1)) { v1 = ov; i1 = oi; }
  }
  const int p = i1;

  // --- step b: hardest positive in masked suffix (argmax, first-index) ---
  const float ppp = pp[p], spp = sp[p];
  const float* __restrict__ Grow = G + (size_t)p * B_N;
  float best = -INFINITY;
  int bestj = 0x7fffffff;
  for (int jb = i & ~63; jb < B_N; jb += 64) {
    const int j = jb + lane;
    const float inner = ppp + zz[j] - 2.0f * Grow[j] +
                        TWO_EPS * (spp - sz[j]) + ZEPS2;
    const float v = fmaxf(inner, 0.0f);
    // per-lane running strict-> keeps lane's first max; global first-index
    // is recovered in the cross-lane reduce below
    if (j >= i && yrel[j] == cls && v > best) { best = v; bestj = j; }
  }
#pragma unroll
  for (int off = 1; off < 64; off <<= 1) {
    float ov = __shfl_xor(best, off, 64);
    int oj = __shfl_xor(bestj, off, 64);
    if (ov > best || (ov == best && oj < bestj)) { best = ov; bestj = oj; }
  }
  const float Dp = sqrtf(best);
  const int jp = bestj;

  // --- step c: logsumexp(-D_n) over proxies ---
  const float zzj = zz[jp], szj = sz[jp];
  const float* __restrict__ GTj = GT + (size_t)jp * 96;
  float d1 = sqrtf(fmaxf(zzj + pp[lane] - 2.0f * GTj[lane] +
                         TWO_EPS * (szj - sp[lane]) + ZEPS2, 0.0f));
  float d2 = INFINITY;
  if (k2 < P_N)
    d2 = sqrtf(fmaxf(zzj + pp[k2] - 2.0f * GTj[k2] +
                     TWO_EPS * (szj - sp[k2]) + ZEPS2, 0.0f));
  const float m = wave_min(fminf(d1, d2));
  float ssum = expf(m - d1) + ((k2 < P_N) ? expf(m - d2) : 0.0f);
  ssum = wave_sum(ssum);
  if (lane == 0) atomicAdd(acc, Dp - m + logf(ssum));
}

// --- kF: mean --------------------------------------------------------------
__global__ void kF(const float* __restrict__ acc, float* __restrict__ out) {
  out[0] = acc[0] * (1.0f / (float)A_N);
}

extern "C" void kernel_launch(void* const* d_in, const int* in_sizes, int n_in,
                              void* d_out, int out_size, void* d_ws, size_t ws_size,
                              hipStream_t stream) {
  const float* z = (const float*)d_in[0];      // [8192,128] f32
  const int* y_idx = (const int*)d_in[1];      // [8192] i32
  const float* prox = (const float*)d_in[2];   // [93,128] f32
  const int* y_map = (const int*)d_in[3];      // [62] i32
  float* out = (float*)d_out;

  // workspace layout (bytes, 512-aligned chunks)
  char* ws = (char*)d_ws;
  float* prxn = (float*)(ws + 0);              // 93*128*4   = 47616
  float* pp   = (float*)(ws + 47616);          // 93*4       -> next 48128
  float* sp   = (float*)(ws + 48128);          //            -> next 48640
  float* zz   = (float*)(ws + 48640);          // 8192*4     -> 81408
  float* sz   = (float*)(ws + 81408);          // 8192*4     -> 114176
  int*   yrel = (int*)  (ws + 114176);         // 8192*4     -> 146944
  float* G    = (float*)(ws + 146944);         // 93*8192*4  -> 3194368
  float* GT   = (float*)(ws + 3194368);        // 8192*96*4  -> 6340096
  float* acc  = (float*)(ws + 6340096);        // 4

  kP<<<P_N, 64, 0, stream>>>(prox, prxn, pp, sp, acc);
  kZ<<<(B_N * 64 + 255) / 256, 256, 0, stream>>>(z, y_idx, y_map, zz, sz, yrel);
  kG<<<dim3(B_N / 256, (P_N + 7) / 8), 256, 0, stream>>>(z, prxn, G, GT);
  kC<<<(A_N * 64 + 255) / 256, 256, 0, stream>>>(zz, sz, yrel, pp, sp, G, GT, acc);
  kF<<<1, 1, 0, stream>>>(acc, out);
}